// Round 10
// baseline (845.479 us; speedup 1.0000x reference)
//
#include <hip/hip_runtime.h>
#include <hip/hip_bf16.h>
#include <cstdint>

#define IN_C 256

typedef __attribute__((ext_vector_type(8))) short bf16x8;
typedef __attribute__((ext_vector_type(8))) short s16x8;
typedef __attribute__((ext_vector_type(4))) short s16x4;
typedef __attribute__((ext_vector_type(4))) float f32x4;

// ---- bf16 split helpers (RNE) ----
__device__ inline unsigned short f2bf(float f) {
    union { float f; unsigned int u; } v; v.f = f;
    unsigned int r = (v.u + 0x7fffu + ((v.u >> 16) & 1u)) >> 16;
    return (unsigned short)r;
}
__device__ inline float bf2f(unsigned short b) {
    union { unsigned int u; float f; } v; v.u = ((unsigned int)b) << 16;
    return v.f;
}
// returns .x = hi bf16 bits, .y = lo bf16 bits
__device__ inline short2 split1(float f) {
    unsigned short hb = f2bf(f);
    unsigned short lb = f2bf(f - bf2f(hb));
    return make_short2((short)hb, (short)lb);
}

// ---------------- init: deg=1 (self loop weight), cnt=0 ----------------
__global__ void init_kernel(float* __restrict__ deg, int* __restrict__ cnt, int N) {
    int i = blockIdx.x * blockDim.x + threadIdx.x;
    if (i < N) { deg[i] = 1.0f; cnt[i] = 0; }
}

// ---------------- per-edge: degree accumulate + dst histogram ----------------
__global__ void deg_count_kernel(const int* __restrict__ ei, const float* __restrict__ w,
                                 float* __restrict__ deg, int* __restrict__ cnt, int E) {
    int e = blockIdx.x * blockDim.x + threadIdx.x;
    if (e >= E) return;
    int dst = ei[E + e];
    atomicAdd(&deg[dst], w[e]);
    atomicAdd(&cnt[dst], 1);
}

// ---------------- exclusive scan of cnt -> row_ptr (3-kernel); scan1 also dinv ----------------
#define SCAN_B 256
__global__ void scan1_kernel(const int* __restrict__ cnt, int* __restrict__ rp,
                             int* __restrict__ bsum,
                             const float* __restrict__ deg, float* __restrict__ dinv,
                             int N) {
    __shared__ int s[SCAN_B];
    int tid = threadIdx.x;
    int i = blockIdx.x * SCAN_B + tid;
    if (i < N) dinv[i] = rsqrtf(deg[i]);      // fused: deg >= 1 always (self loop)
    int v = (i < N) ? cnt[i] : 0;
    s[tid] = v;
    __syncthreads();
    for (int off = 1; off < SCAN_B; off <<= 1) {
        int t = (tid >= off) ? s[tid - off] : 0;
        __syncthreads();
        s[tid] += t;
        __syncthreads();
    }
    if (i < N) rp[i] = s[tid] - v;            // exclusive within block
    if (tid == SCAN_B - 1) bsum[blockIdx.x] = s[tid];
}

__global__ void scan2_kernel(int* __restrict__ bsum, int* __restrict__ boff, int nb) {
    __shared__ int s[SCAN_B];
    int tid = threadIdx.x;
    int v = (tid < nb) ? bsum[tid] : 0;
    s[tid] = v;
    __syncthreads();
    for (int off = 1; off < SCAN_B; off <<= 1) {
        int t = (tid >= off) ? s[tid - off] : 0;
        __syncthreads();
        s[tid] += t;
        __syncthreads();
    }
    if (tid < nb) boff[tid] = s[tid] - v;     // exclusive across blocks
}

__global__ void scan3_kernel(int* __restrict__ rp, int* __restrict__ cursor,
                             const int* __restrict__ boff, int N, int E) {
    int i = blockIdx.x * blockDim.x + threadIdx.x;
    if (i < N) {
        int r = rp[i] + boff[i >> 8];
        rp[i] = r;
        cursor[i] = r;
    }
    if (i == 0) rp[N] = E;
}

// ---------------- CSR fill with per-edge norm ----------------
__global__ void fill_kernel(const int* __restrict__ ei, const float* __restrict__ w,
                            const float* __restrict__ dinv, int* __restrict__ cursor,
                            int* __restrict__ col, float* __restrict__ val, int E) {
    int e = blockIdx.x * blockDim.x + threadIdx.x;
    if (e >= E) return;
    int src = ei[e];
    int dst = ei[E + e];
    int pos = atomicAdd(&cursor[dst], 1);
    // defensive clamp: never allow a wild store outside [0,E)
    if (pos >= 0 && pos < E) {
        col[pos] = src;
        val[pos] = dinv[src] * w[e] * dinv[dst];
    }
}

// ---------------- W prep: transpose + bf16 hi/lo split (W1 and W2 in one launch) ----------------
__global__ void prep_w_kernel(const float* __restrict__ W1, const float* __restrict__ W2,
                              unsigned short* __restrict__ w1t_hi, unsigned short* __restrict__ w1t_lo,
                              unsigned short* __restrict__ w2t_hi, unsigned short* __restrict__ w2t_lo) {
    int b = blockIdx.x;
    const float* W = (b < 256) ? W1 : W2;
    unsigned short* hi = (b < 256) ? w1t_hi : w2t_hi;
    unsigned short* lo = (b < 256) ? w1t_lo : w2t_lo;
    int n = b & 255;       // col of W
    int k = threadIdx.x;   // row of W
    float v = W[(size_t)k * 256 + n];
    short2 s = split1(v);
    hi[(size_t)n * 256 + k] = (unsigned short)s.x;
    lo[(size_t)n * 256 + k] = (unsigned short)s.y;
}

// ---------------- split-bf16 MFMA GEMM ----------------
// C[N][256] (fp32) = A[N][256] @ B[256][256] in ~fp32 precision via 3x bf16 MFMA.
// Block: 256 thr = 4 waves; tile 128 rows x 128 cols; BK=64, single-buffered LDS.
// AFP32: A is fp32, split on the fly. else: A pre-split hi/lo bf16 arrays.
template<bool AFP32>
__global__ __launch_bounds__(256) void gemm_split_kernel(
    const float* __restrict__ Af,
    const unsigned short* __restrict__ Ahg,
    const unsigned short* __restrict__ Alg,
    const unsigned short* __restrict__ Bth,   // Wt_hi [n][k]
    const unsigned short* __restrict__ Btl,   // Wt_lo [n][k]
    float* __restrict__ C, int Nrows)
{
    __shared__ __align__(16) short Ah[128 * 64];
    __shared__ __align__(16) short Al[128 * 64];
    __shared__ __align__(16) short Bh[128 * 64];
    __shared__ __align__(16) short Bl[128 * 64];

    const int t    = threadIdx.x;
    const int lane = t & 63;
    const int w    = t >> 6;
    const int r0   = blockIdx.x * 128;
    const int cb0  = blockIdx.y * 128;
    const int fr   = lane & 15;          // frag row (A: m-row / B: n-col)
    const int fk   = (lane >> 4) * 8;    // frag k offset
    const int wm   = w * 32;             // wave's m-band

    f32x4 acc[2][8] = {};

    for (int k0 = 0; k0 < 256; k0 += 64) {
        __syncthreads();
        // ---- stage B tile [128 n][64 k] (hi+lo) ----
#pragma unroll
        for (int c = 0; c < 4; ++c) {
            int i = c * 256 + t;
            int row = i >> 3, seg = i & 7;
            size_t g = (size_t)(cb0 + row) * 256 + k0 + seg * 8;
            *(s16x8*)&Bh[row * 64 + seg * 8] = *(const s16x8*)(Bth + g);
            *(s16x8*)&Bl[row * 64 + seg * 8] = *(const s16x8*)(Btl + g);
        }
        // ---- stage A tile [128 m][64 k] (hi+lo) ----
        if constexpr (AFP32) {
#pragma unroll
            for (int c = 0; c < 8; ++c) {
                int i = c * 256 + t;
                int row = i >> 4, seg = i & 15;
                int gr = r0 + row; if (gr > Nrows - 1) gr = Nrows - 1;
                float4 v = *(const float4*)(Af + (size_t)gr * 256 + k0 + seg * 4);
                short2 sx = split1(v.x);
                short2 sy = split1(v.y);
                short2 sz = split1(v.z);
                short2 sw = split1(v.w);
                s16x4 hv, lv;
                hv.x = sx.x; hv.y = sy.x; hv.z = sz.x; hv.w = sw.x;
                lv.x = sx.y; lv.y = sy.y; lv.z = sz.y; lv.w = sw.y;
                *(s16x4*)&Ah[row * 64 + seg * 4] = hv;
                *(s16x4*)&Al[row * 64 + seg * 4] = lv;
            }
        } else {
#pragma unroll
            for (int c = 0; c < 4; ++c) {
                int i = c * 256 + t;
                int row = i >> 3, seg = i & 7;
                int gr = r0 + row; if (gr > Nrows - 1) gr = Nrows - 1;
                size_t g = (size_t)gr * 256 + k0 + seg * 8;
                *(s16x8*)&Ah[row * 64 + seg * 8] = *(const s16x8*)(Ahg + g);
                *(s16x8*)&Al[row * 64 + seg * 8] = *(const s16x8*)(Alg + g);
            }
        }
        __syncthreads();
        // ---- compute: 2 k-steps of 32, 2m x 8n frags, 3 MFMA each ----
#pragma unroll
        for (int ks = 0; ks < 2; ++ks) {
            int ko = ks * 32 + fk;
            bf16x8 ah[2], al[2];
#pragma unroll
            for (int mi = 0; mi < 2; ++mi) {
                ah[mi] = *(const bf16x8*)&Ah[(wm + mi * 16 + fr) * 64 + ko];
                al[mi] = *(const bf16x8*)&Al[(wm + mi * 16 + fr) * 64 + ko];
            }
#pragma unroll
            for (int n = 0; n < 8; ++n) {
                bf16x8 bh = *(const bf16x8*)&Bh[(n * 16 + fr) * 64 + ko];
                bf16x8 bl = *(const bf16x8*)&Bl[(n * 16 + fr) * 64 + ko];
#pragma unroll
                for (int mi = 0; mi < 2; ++mi) {
                    acc[mi][n] = __builtin_amdgcn_mfma_f32_16x16x32_bf16(ah[mi], bh, acc[mi][n], 0, 0, 0);
                    acc[mi][n] = __builtin_amdgcn_mfma_f32_16x16x32_bf16(ah[mi], bl, acc[mi][n], 0, 0, 0);
                    acc[mi][n] = __builtin_amdgcn_mfma_f32_16x16x32_bf16(al[mi], bh, acc[mi][n], 0, 0, 0);
                }
            }
        }
    }
    // ---- epilogue: C/D layout col=lane&15, row=(lane>>4)*4+reg; store fp32 ----
    const int rb = (lane >> 4) * 4;
#pragma unroll
    for (int mi = 0; mi < 2; ++mi) {
#pragma unroll
        for (int n = 0; n < 8; ++n) {
            int col = cb0 + n * 16 + fr;
#pragma unroll
            for (int r = 0; r < 4; ++r) {
                int row = r0 + wm + mi * 16 + rb + r;
                if (row < Nrows) C[(size_t)row * 256 + col] = acc[mi][n][r];
            }
        }
    }
}

// ---------------- CSR aggregation + self loop + bias + relu (+optional fused head) ----
// R4-exact gather structure (VGPR=40, 225us measured): one WAVE per dst node;
// lane l owns channels [4l,4l+4); unroll-by-8 edge loop with fp32 float4
// gathers (8 independent 1KB row-gathers in flight).
// Epilogue (runtime pointer dispatch):
//   out_hi != nullptr : relu + write bf16 hi/lo split (feeds next MFMA GEMM)
//   else              : relu + fused regression head (dot Wf, wave-reduce, 1 float)
// NOTE: bf16 h-gather (ushort4) was tried in R6/R7 and is 6.7x SLOWER despite
// half the bytes — do not reintroduce.
__global__ __launch_bounds__(256) void agg_kernel(const float* __restrict__ h,
                                                  const int* __restrict__ rp,
                                                  const int* __restrict__ col,
                                                  const float* __restrict__ val,
                                                  const float* __restrict__ dinv,
                                                  const float* __restrict__ bias,
                                                  unsigned short* __restrict__ out_hi,
                                                  unsigned short* __restrict__ out_lo,
                                                  const float* __restrict__ Wf,
                                                  const float* __restrict__ bf,
                                                  float* __restrict__ out,
                                                  int N) {
    int d    = blockIdx.x * 4 + (threadIdx.x >> 6);
    int lane = threadIdx.x & 63;
    if (d >= N) return;
    const float4* __restrict__ h4 = (const float4*)h;   // row stride = 64 float4

    float di = dinv[d];
    float4 hv = h4[(size_t)d * 64 + lane];
    float self = di * di;                                // self loop, weight 1
    float4 acc;
    acc.x = self * hv.x; acc.y = self * hv.y;
    acc.z = self * hv.z; acc.w = self * hv.w;

    int s = rp[d], e = rp[d + 1];
    int j = s;
    for (; j + 8 <= e; j += 8) {
        int   c0 = col[j],     c1 = col[j + 1], c2 = col[j + 2], c3 = col[j + 3];
        int   c4 = col[j + 4], c5 = col[j + 5], c6 = col[j + 6], c7 = col[j + 7];
        float v0 = val[j],     v1 = val[j + 1], v2 = val[j + 2], v3 = val[j + 3];
        float v4 = val[j + 4], v5 = val[j + 5], v6 = val[j + 6], v7 = val[j + 7];
        float4 a0 = h4[(size_t)c0 * 64 + lane];
        float4 a1 = h4[(size_t)c1 * 64 + lane];
        float4 a2 = h4[(size_t)c2 * 64 + lane];
        float4 a3 = h4[(size_t)c3 * 64 + lane];
        float4 a4 = h4[(size_t)c4 * 64 + lane];
        float4 a5 = h4[(size_t)c5 * 64 + lane];
        float4 a6 = h4[(size_t)c6 * 64 + lane];
        float4 a7 = h4[(size_t)c7 * 64 + lane];
        acc.x = fmaf(v0, a0.x, acc.x); acc.y = fmaf(v0, a0.y, acc.y);
        acc.z = fmaf(v0, a0.z, acc.z); acc.w = fmaf(v0, a0.w, acc.w);
        acc.x = fmaf(v1, a1.x, acc.x); acc.y = fmaf(v1, a1.y, acc.y);
        acc.z = fmaf(v1, a1.z, acc.z); acc.w = fmaf(v1, a1.w, acc.w);
        acc.x = fmaf(v2, a2.x, acc.x); acc.y = fmaf(v2, a2.y, acc.y);
        acc.z = fmaf(v2, a2.z, acc.z); acc.w = fmaf(v2, a2.w, acc.w);
        acc.x = fmaf(v3, a3.x, acc.x); acc.y = fmaf(v3, a3.y, acc.y);
        acc.z = fmaf(v3, a3.z, acc.z); acc.w = fmaf(v3, a3.w, acc.w);
        acc.x = fmaf(v4, a4.x, acc.x); acc.y = fmaf(v4, a4.y, acc.y);
        acc.z = fmaf(v4, a4.z, acc.z); acc.w = fmaf(v4, a4.w, acc.w);
        acc.x = fmaf(v5, a5.x, acc.x); acc.y = fmaf(v5, a5.y, acc.y);
        acc.z = fmaf(v5, a5.z, acc.z); acc.w = fmaf(v5, a5.w, acc.w);
        acc.x = fmaf(v6, a6.x, acc.x); acc.y = fmaf(v6, a6.y, acc.y);
        acc.z = fmaf(v6, a6.z, acc.z); acc.w = fmaf(v6, a6.w, acc.w);
        acc.x = fmaf(v7, a7.x, acc.x); acc.y = fmaf(v7, a7.y, acc.y);
        acc.z = fmaf(v7, a7.z, acc.z); acc.w = fmaf(v7, a7.w, acc.w);
    }
    for (; j < e; ++j) {
        int   c = col[j];
        float v = val[j];
        float4 a = h4[(size_t)c * 64 + lane];
        acc.x = fmaf(v, a.x, acc.x); acc.y = fmaf(v, a.y, acc.y);
        acc.z = fmaf(v, a.z, acc.z); acc.w = fmaf(v, a.w, acc.w);
    }

    float4 b = *(const float4*)(bias + lane * 4);
    acc.x = fmaxf(acc.x + b.x, 0.0f);
    acc.y = fmaxf(acc.y + b.y, 0.0f);
    acc.z = fmaxf(acc.z + b.z, 0.0f);
    acc.w = fmaxf(acc.w + b.w, 0.0f);

    if (out_hi != nullptr) {
        short2 sx = split1(acc.x);
        short2 sy = split1(acc.y);
        short2 sz = split1(acc.z);
        short2 sw = split1(acc.w);
        s16x4 hvv, lvv;
        hvv.x = sx.x; hvv.y = sy.x; hvv.z = sz.x; hvv.w = sw.x;
        lvv.x = sx.y; lvv.y = sy.y; lvv.z = sz.y; lvv.w = sw.y;
        *(s16x4*)(out_hi + (size_t)d * 256 + lane * 4) = hvv;
        *(s16x4*)(out_lo + (size_t)d * 256 + lane * 4) = lvv;
    } else {
        float4 wf = *(const float4*)(Wf + lane * 4);
        float sdot = acc.x * wf.x + acc.y * wf.y + acc.z * wf.z + acc.w * wf.w;
        for (int off = 32; off; off >>= 1) sdot += __shfl_down(sdot, off);
        if (lane == 0) out[d] = sdot + bf[0];
    }
}

// ---------------- host launch ----------------
extern "C" void kernel_launch(void* const* d_in, const int* in_sizes, int n_in,
                              void* d_out, int out_size, void* d_ws, size_t ws_size,
                              hipStream_t stream) {
    const float* x  = (const float*)d_in[0];
    const int*   ei = (const int*)d_in[1];
    const float* w  = (const float*)d_in[2];
    const float* W1 = (const float*)d_in[3];
    const float* b1 = (const float*)d_in[4];
    const float* W2 = (const float*)d_in[5];
    const float* b2 = (const float*)d_in[6];
    const float* Wf = (const float*)d_in[7];
    const float* bf = (const float*)d_in[8];
    float* out = (float*)d_out;

    const int N = in_sizes[0] / IN_C;
    const int E = in_sizes[2];

    // workspace layout (256B aligned)
    auto align256 = [](size_t v) { return (v + 255) & ~(size_t)255; };
    char* p = (char*)d_ws;
    float* deg    = (float*)p; p += align256((size_t)N * 4);
    float* dinv   = (float*)p; p += align256((size_t)N * 4);
    int*   cnt    = (int*)p;   p += align256((size_t)N * 4);
    int*   rp     = (int*)p;   p += align256(((size_t)N + 1) * 4);
    int*   cursor = (int*)p;   p += align256((size_t)N * 4);
    int*   bsum   = (int*)p;   p += align256(SCAN_B * 4);
    int*   boff   = (int*)p;   p += align256(SCAN_B * 4);
    int*   col    = (int*)p;   p += align256((size_t)E * 4);
    float* val    = (float*)p; p += align256((size_t)E * 4);
    unsigned short* w1t_hi = (unsigned short*)p; p += align256((size_t)256 * 256 * 2);
    unsigned short* w1t_lo = (unsigned short*)p; p += align256((size_t)256 * 256 * 2);
    unsigned short* w2t_hi = (unsigned short*)p; p += align256((size_t)256 * 256 * 2);
    unsigned short* w2t_lo = (unsigned short*)p; p += align256((size_t)256 * 256 * 2);
    float* hbuf   = (float*)p; p += align256((size_t)N * 256 * 4);
    unsigned short* a_hi = (unsigned short*)p; p += align256((size_t)N * 256 * 2);
    unsigned short* a_lo = (unsigned short*)p; p += align256((size_t)N * 256 * 2);
    (void)ws_size; (void)n_in; (void)out_size;

    const int nb_nodes = (N + 255) / 256;
    const int nb_edges = (E + 255) / 256;
    const int nb_scan  = (N + SCAN_B - 1) / SCAN_B;

    // graph normalization + CSR build
    init_kernel<<<nb_nodes, 256, 0, stream>>>(deg, cnt, N);
    deg_count_kernel<<<nb_edges, 256, 0, stream>>>(ei, w, deg, cnt, E);
    scan1_kernel<<<nb_scan, SCAN_B, 0, stream>>>(cnt, rp, bsum, deg, dinv, N);
    scan2_kernel<<<1, SCAN_B, 0, stream>>>(bsum, boff, nb_scan);
    scan3_kernel<<<nb_nodes, 256, 0, stream>>>(rp, cursor, boff, N, E);
    fill_kernel<<<nb_edges, 256, 0, stream>>>(ei, w, dinv, cursor, col, val, E);

    // weight prep (transpose + hi/lo split), both W in one launch
    prep_w_kernel<<<512, 256, 0, stream>>>(W1, W2, w1t_hi, w1t_lo, w2t_hi, w2t_lo);

    dim3 ggrid((N + 127) / 128, 2);
    const int nb_agg = (N + 3) / 4;

    // layer 1: GEMM (fp32 A, on-the-fly split) -> fp32 h -> agg (writes bf16 hi/lo)
    gemm_split_kernel<true><<<ggrid, 256, 0, stream>>>(x, nullptr, nullptr,
                                                       w1t_hi, w1t_lo, hbuf, N);
    agg_kernel<<<nb_agg, 256, 0, stream>>>(hbuf, rp, col, val, dinv, b1,
                                           a_hi, a_lo, nullptr, nullptr, nullptr, N);
    // layer 2: GEMM (pre-split bf16 A) -> fp32 h -> agg + fused head
    gemm_split_kernel<false><<<ggrid, 256, 0, stream>>>(nullptr, a_hi, a_lo,
                                                        w2t_hi, w2t_lo, hbuf, N);
    agg_kernel<<<nb_agg, 256, 0, stream>>>(hbuf, rp, col, val, dinv, b2,
                                           nullptr, nullptr, Wf, bf, out, N);
}

// Round 11
// 729.489 us; speedup vs baseline: 1.1590x; 1.1590x over previous
//
#include <hip/hip_runtime.h>
#include <hip/hip_bf16.h>
#include <cstdint>

#define IN_C 256

typedef __attribute__((ext_vector_type(8))) short bf16x8;
typedef __attribute__((ext_vector_type(8))) short s16x8;
typedef __attribute__((ext_vector_type(4))) short s16x4;
typedef __attribute__((ext_vector_type(8))) unsigned short u16x8;
typedef __attribute__((ext_vector_type(4))) float f32x4;

// ---- bf16 split helpers (RNE) ----
__device__ inline unsigned short f2bf(float f) {
    union { float f; unsigned int u; } v; v.f = f;
    unsigned int r = (v.u + 0x7fffu + ((v.u >> 16) & 1u)) >> 16;
    return (unsigned short)r;
}
__device__ inline float bf2f(unsigned short b) {
    union { unsigned int u; float f; } v; v.u = ((unsigned int)b) << 16;
    return v.f;
}
// returns .x = hi bf16 bits, .y = lo bf16 bits
__device__ inline short2 split1(float f) {
    unsigned short hb = f2bf(f);
    unsigned short lb = f2bf(f - bf2f(hb));
    return make_short2((short)hb, (short)lb);
}

// ---------------- init: deg=1 (self loop weight), cnt=0 ----------------
__global__ void init_kernel(float* __restrict__ deg, int* __restrict__ cnt, int N) {
    int i = blockIdx.x * blockDim.x + threadIdx.x;
    if (i < N) { deg[i] = 1.0f; cnt[i] = 0; }
}

// ---------------- per-edge: degree accumulate + dst histogram ----------------
__global__ void deg_count_kernel(const int* __restrict__ ei, const float* __restrict__ w,
                                 float* __restrict__ deg, int* __restrict__ cnt, int E) {
    int e = blockIdx.x * blockDim.x + threadIdx.x;
    if (e >= E) return;
    int dst = ei[E + e];
    atomicAdd(&deg[dst], w[e]);
    atomicAdd(&cnt[dst], 1);
}

// ---------------- exclusive scan of cnt -> row_ptr (3-kernel); scan1 also dinv ----------------
#define SCAN_B 256
__global__ void scan1_kernel(const int* __restrict__ cnt, int* __restrict__ rp,
                             int* __restrict__ bsum,
                             const float* __restrict__ deg, float* __restrict__ dinv,
                             int N) {
    __shared__ int s[SCAN_B];
    int tid = threadIdx.x;
    int i = blockIdx.x * SCAN_B + tid;
    if (i < N) dinv[i] = rsqrtf(deg[i]);      // fused: deg >= 1 always (self loop)
    int v = (i < N) ? cnt[i] : 0;
    s[tid] = v;
    __syncthreads();
    for (int off = 1; off < SCAN_B; off <<= 1) {
        int t = (tid >= off) ? s[tid - off] : 0;
        __syncthreads();
        s[tid] += t;
        __syncthreads();
    }
    if (i < N) rp[i] = s[tid] - v;            // exclusive within block
    if (tid == SCAN_B - 1) bsum[blockIdx.x] = s[tid];
}

__global__ void scan2_kernel(int* __restrict__ bsum, int* __restrict__ boff, int nb) {
    __shared__ int s[SCAN_B];
    int tid = threadIdx.x;
    int v = (tid < nb) ? bsum[tid] : 0;
    s[tid] = v;
    __syncthreads();
    for (int off = 1; off < SCAN_B; off <<= 1) {
        int t = (tid >= off) ? s[tid - off] : 0;
        __syncthreads();
        s[tid] += t;
        __syncthreads();
    }
    if (tid < nb) boff[tid] = s[tid] - v;     // exclusive across blocks
}

__global__ void scan3_kernel(int* __restrict__ rp, int* __restrict__ cursor,
                             const int* __restrict__ boff, int N, int E) {
    int i = blockIdx.x * blockDim.x + threadIdx.x;
    if (i < N) {
        int r = rp[i] + boff[i >> 8];
        rp[i] = r;
        cursor[i] = r;
    }
    if (i == 0) rp[N] = E;
}

// ---------------- CSR fill with per-edge norm ----------------
__global__ void fill_kernel(const int* __restrict__ ei, const float* __restrict__ w,
                            const float* __restrict__ dinv, int* __restrict__ cursor,
                            int* __restrict__ col, float* __restrict__ val, int E) {
    int e = blockIdx.x * blockDim.x + threadIdx.x;
    if (e >= E) return;
    int src = ei[e];
    int dst = ei[E + e];
    int pos = atomicAdd(&cursor[dst], 1);
    // defensive clamp: never allow a wild store outside [0,E)
    if (pos >= 0 && pos < E) {
        col[pos] = src;
        val[pos] = dinv[src] * w[e] * dinv[dst];
    }
}

// ---------------- W prep: transpose + bf16 hi/lo split (W1 and W2 in one launch) ----------------
__global__ void prep_w_kernel(const float* __restrict__ W1, const float* __restrict__ W2,
                              unsigned short* __restrict__ w1t_hi, unsigned short* __restrict__ w1t_lo,
                              unsigned short* __restrict__ w2t_hi, unsigned short* __restrict__ w2t_lo) {
    int b = blockIdx.x;
    const float* W = (b < 256) ? W1 : W2;
    unsigned short* hi = (b < 256) ? w1t_hi : w2t_hi;
    unsigned short* lo = (b < 256) ? w1t_lo : w2t_lo;
    int n = b & 255;       // col of W
    int k = threadIdx.x;   // row of W
    float v = W[(size_t)k * 256 + n];
    short2 s = split1(v);
    hi[(size_t)n * 256 + k] = (unsigned short)s.x;
    lo[(size_t)n * 256 + k] = (unsigned short)s.y;
}

// ---------------- split-bf16 MFMA GEMM ----------------
// C16[N][256] (plain bf16) = A[N][256] @ B[256][256] in ~fp32 precision via 3x bf16 MFMA.
// Block: 256 thr = 4 waves; tile 128 rows x 128 cols; BK=64, single-buffered LDS.
// AFP32: A is fp32, split on the fly. else: A pre-split hi/lo bf16 arrays.
template<bool AFP32>
__global__ __launch_bounds__(256) void gemm_split_kernel(
    const float* __restrict__ Af,
    const unsigned short* __restrict__ Ahg,
    const unsigned short* __restrict__ Alg,
    const unsigned short* __restrict__ Bth,   // Wt_hi [n][k]
    const unsigned short* __restrict__ Btl,   // Wt_lo [n][k]
    unsigned short* __restrict__ C16, int Nrows)
{
    __shared__ __align__(16) short Ah[128 * 64];
    __shared__ __align__(16) short Al[128 * 64];
    __shared__ __align__(16) short Bh[128 * 64];
    __shared__ __align__(16) short Bl[128 * 64];

    const int t    = threadIdx.x;
    const int lane = t & 63;
    const int w    = t >> 6;
    const int r0   = blockIdx.x * 128;
    const int cb0  = blockIdx.y * 128;
    const int fr   = lane & 15;          // frag row (A: m-row / B: n-col)
    const int fk   = (lane >> 4) * 8;    // frag k offset
    const int wm   = w * 32;             // wave's m-band

    f32x4 acc[2][8] = {};

    for (int k0 = 0; k0 < 256; k0 += 64) {
        __syncthreads();
        // ---- stage B tile [128 n][64 k] (hi+lo) ----
#pragma unroll
        for (int c = 0; c < 4; ++c) {
            int i = c * 256 + t;
            int row = i >> 3, seg = i & 7;
            size_t g = (size_t)(cb0 + row) * 256 + k0 + seg * 8;
            *(s16x8*)&Bh[row * 64 + seg * 8] = *(const s16x8*)(Bth + g);
            *(s16x8*)&Bl[row * 64 + seg * 8] = *(const s16x8*)(Btl + g);
        }
        // ---- stage A tile [128 m][64 k] (hi+lo) ----
        if constexpr (AFP32) {
#pragma unroll
            for (int c = 0; c < 8; ++c) {
                int i = c * 256 + t;
                int row = i >> 4, seg = i & 15;
                int gr = r0 + row; if (gr > Nrows - 1) gr = Nrows - 1;
                float4 v = *(const float4*)(Af + (size_t)gr * 256 + k0 + seg * 4);
                short2 sx = split1(v.x);
                short2 sy = split1(v.y);
                short2 sz = split1(v.z);
                short2 sw = split1(v.w);
                s16x4 hv, lv;
                hv.x = sx.x; hv.y = sy.x; hv.z = sz.x; hv.w = sw.x;
                lv.x = sx.y; lv.y = sy.y; lv.z = sz.y; lv.w = sw.y;
                *(s16x4*)&Ah[row * 64 + seg * 4] = hv;
                *(s16x4*)&Al[row * 64 + seg * 4] = lv;
            }
        } else {
#pragma unroll
            for (int c = 0; c < 4; ++c) {
                int i = c * 256 + t;
                int row = i >> 3, seg = i & 7;
                int gr = r0 + row; if (gr > Nrows - 1) gr = Nrows - 1;
                size_t g = (size_t)gr * 256 + k0 + seg * 8;
                *(s16x8*)&Ah[row * 64 + seg * 8] = *(const s16x8*)(Ahg + g);
                *(s16x8*)&Al[row * 64 + seg * 8] = *(const s16x8*)(Alg + g);
            }
        }
        __syncthreads();
        // ---- compute: 2 k-steps of 32, 2m x 8n frags, 3 MFMA each ----
#pragma unroll
        for (int ks = 0; ks < 2; ++ks) {
            int ko = ks * 32 + fk;
            bf16x8 ah[2], al[2];
#pragma unroll
            for (int mi = 0; mi < 2; ++mi) {
                ah[mi] = *(const bf16x8*)&Ah[(wm + mi * 16 + fr) * 64 + ko];
                al[mi] = *(const bf16x8*)&Al[(wm + mi * 16 + fr) * 64 + ko];
            }
#pragma unroll
            for (int n = 0; n < 8; ++n) {
                bf16x8 bh = *(const bf16x8*)&Bh[(n * 16 + fr) * 64 + ko];
                bf16x8 bl = *(const bf16x8*)&Bl[(n * 16 + fr) * 64 + ko];
#pragma unroll
                for (int mi = 0; mi < 2; ++mi) {
                    acc[mi][n] = __builtin_amdgcn_mfma_f32_16x16x32_bf16(ah[mi], bh, acc[mi][n], 0, 0, 0);
                    acc[mi][n] = __builtin_amdgcn_mfma_f32_16x16x32_bf16(ah[mi], bl, acc[mi][n], 0, 0, 0);
                    acc[mi][n] = __builtin_amdgcn_mfma_f32_16x16x32_bf16(al[mi], bh, acc[mi][n], 0, 0, 0);
                }
            }
        }
    }
    // ---- epilogue: C/D layout col=lane&15, row=(lane>>4)*4+reg; store plain bf16 ----
    const int rb = (lane >> 4) * 4;
#pragma unroll
    for (int mi = 0; mi < 2; ++mi) {
#pragma unroll
        for (int n = 0; n < 8; ++n) {
            int col = cb0 + n * 16 + fr;
#pragma unroll
            for (int r = 0; r < 4; ++r) {
                int row = r0 + wm + mi * 16 + rb + r;
                if (row < Nrows) C16[(size_t)row * 256 + col] = f2bf(acc[mi][n][r]);
            }
        }
    }
}

// ---- 8-channel bf16 FMA helper ----
__device__ inline void fma8(float* acc, u16x8 g, float v) {
#pragma unroll
    for (int c = 0; c < 8; ++c) acc[c] = fmaf(v, bf2f(g[c]), acc[c]);
}

// ---------------- CSR aggregation + self loop + bias + relu (+optional fused head) ----
// bf16-h gather, HALF-WAVE-per-edge structure: keeps the proven 16B/lane
// global_load_dwordx4 shape (R6/R7's 8B ushort4 loads collapsed to ~2 in
// flight, 6.7x slower). One wave per dst node; lane l handles 8 channels
// [8*(l&31), +8) of edge j+2t+(l>>5); 8 dwordx4 gathers (16 edges) in flight.
// col/val are wave-uniform scalar loads + per-lane cndmask. Cross-half
// shfl_xor(32) combine; self loop gated to half 0.
// Epilogue (runtime pointer dispatch):
//   out_hi != nullptr : relu + bf16 hi/lo split (half0 writes hi, half1 lo)
//   else              : relu + fused regression head (dot Wf, per-half reduce)
__global__ __launch_bounds__(256) void agg_kernel(const unsigned short* __restrict__ h16,
                                                  const int* __restrict__ rp,
                                                  const int* __restrict__ col,
                                                  const float* __restrict__ val,
                                                  const float* __restrict__ dinv,
                                                  const float* __restrict__ bias,
                                                  unsigned short* __restrict__ out_hi,
                                                  unsigned short* __restrict__ out_lo,
                                                  const float* __restrict__ Wf,
                                                  const float* __restrict__ bf,
                                                  float* __restrict__ out,
                                                  int N) {
    int d    = blockIdx.x * 4 + (threadIdx.x >> 6);
    int lane = threadIdx.x & 63;
    if (d >= N) return;
    int half = lane >> 5;
    int co   = (lane & 31) * 8;          // this lane's channel offset

    float di = dinv[d];
    float selfm = half ? 0.0f : di * di;           // count self loop once
    u16x8 sv = *(const u16x8*)(h16 + (size_t)d * 256 + co);
    float acc[8];
#pragma unroll
    for (int c = 0; c < 8; ++c) acc[c] = selfm * bf2f(sv[c]);

    int s = rp[d], e = rp[d + 1];
    int j = s;
    for (; j + 16 <= e; j += 16) {
        int   e0 = half ? col[j + 1]  : col[j + 0];
        int   e1 = half ? col[j + 3]  : col[j + 2];
        int   e2 = half ? col[j + 5]  : col[j + 4];
        int   e3 = half ? col[j + 7]  : col[j + 6];
        int   e4 = half ? col[j + 9]  : col[j + 8];
        int   e5 = half ? col[j + 11] : col[j + 10];
        int   e6 = half ? col[j + 13] : col[j + 12];
        int   e7 = half ? col[j + 15] : col[j + 14];
        float v0 = half ? val[j + 1]  : val[j + 0];
        float v1 = half ? val[j + 3]  : val[j + 2];
        float v2 = half ? val[j + 5]  : val[j + 4];
        float v3 = half ? val[j + 7]  : val[j + 6];
        float v4 = half ? val[j + 9]  : val[j + 8];
        float v5 = half ? val[j + 11] : val[j + 10];
        float v6 = half ? val[j + 13] : val[j + 12];
        float v7 = half ? val[j + 15] : val[j + 14];
        u16x8 g0 = *(const u16x8*)(h16 + (size_t)e0 * 256 + co);
        u16x8 g1 = *(const u16x8*)(h16 + (size_t)e1 * 256 + co);
        u16x8 g2 = *(const u16x8*)(h16 + (size_t)e2 * 256 + co);
        u16x8 g3 = *(const u16x8*)(h16 + (size_t)e3 * 256 + co);
        u16x8 g4 = *(const u16x8*)(h16 + (size_t)e4 * 256 + co);
        u16x8 g5 = *(const u16x8*)(h16 + (size_t)e5 * 256 + co);
        u16x8 g6 = *(const u16x8*)(h16 + (size_t)e6 * 256 + co);
        u16x8 g7 = *(const u16x8*)(h16 + (size_t)e7 * 256 + co);
        fma8(acc, g0, v0);
        fma8(acc, g1, v1);
        fma8(acc, g2, v2);
        fma8(acc, g3, v3);
        fma8(acc, g4, v4);
        fma8(acc, g5, v5);
        fma8(acc, g6, v6);
        fma8(acc, g7, v7);
    }
    for (; j + 2 <= e; j += 2) {
        int   ee = half ? col[j + 1] : col[j];
        float vv = half ? val[j + 1] : val[j];
        u16x8 g = *(const u16x8*)(h16 + (size_t)ee * 256 + co);
        fma8(acc, g, vv);
    }
    if (j < e) {                                    // single leftover edge
        int   ee = col[j];
        float vv = half ? 0.0f : val[j];
        u16x8 g = *(const u16x8*)(h16 + (size_t)ee * 256 + co);
        fma8(acc, g, vv);
    }

    // combine halves: both halves end with the full per-channel sums
#pragma unroll
    for (int c = 0; c < 8; ++c) acc[c] += __shfl_xor(acc[c], 32);

    float4 b0 = *(const float4*)(bias + co);
    float4 b1 = *(const float4*)(bias + co + 4);
    acc[0] = fmaxf(acc[0] + b0.x, 0.0f);
    acc[1] = fmaxf(acc[1] + b0.y, 0.0f);
    acc[2] = fmaxf(acc[2] + b0.z, 0.0f);
    acc[3] = fmaxf(acc[3] + b0.w, 0.0f);
    acc[4] = fmaxf(acc[4] + b1.x, 0.0f);
    acc[5] = fmaxf(acc[5] + b1.y, 0.0f);
    acc[6] = fmaxf(acc[6] + b1.z, 0.0f);
    acc[7] = fmaxf(acc[7] + b1.w, 0.0f);

    if (out_hi != nullptr) {
        u16x8 hi;
#pragma unroll
        for (int c = 0; c < 8; ++c) hi[c] = f2bf(acc[c]);
        if (half == 0) {
            *(u16x8*)(out_hi + (size_t)d * 256 + co) = hi;
        } else {
            u16x8 lo;
#pragma unroll
            for (int c = 0; c < 8; ++c) lo[c] = f2bf(acc[c] - bf2f(hi[c]));
            *(u16x8*)(out_lo + (size_t)d * 256 + co) = lo;
        }
    } else {
        float4 wf0 = *(const float4*)(Wf + co);
        float4 wf1 = *(const float4*)(Wf + co + 4);
        float sdot = acc[0] * wf0.x + acc[1] * wf0.y + acc[2] * wf0.z + acc[3] * wf0.w
                   + acc[4] * wf1.x + acc[5] * wf1.y + acc[6] * wf1.z + acc[7] * wf1.w;
        for (int o = 16; o; o >>= 1) sdot += __shfl_down(sdot, o);   // per-half reduce
        if (lane == 0) out[d] = sdot + bf[0];
    }
}

// ---------------- host launch ----------------
extern "C" void kernel_launch(void* const* d_in, const int* in_sizes, int n_in,
                              void* d_out, int out_size, void* d_ws, size_t ws_size,
                              hipStream_t stream) {
    const float* x  = (const float*)d_in[0];
    const int*   ei = (const int*)d_in[1];
    const float* w  = (const float*)d_in[2];
    const float* W1 = (const float*)d_in[3];
    const float* b1 = (const float*)d_in[4];
    const float* W2 = (const float*)d_in[5];
    const float* b2 = (const float*)d_in[6];
    const float* Wf = (const float*)d_in[7];
    const float* bf = (const float*)d_in[8];
    float* out = (float*)d_out;

    const int N = in_sizes[0] / IN_C;
    const int E = in_sizes[2];

    // workspace layout (256B aligned)
    auto align256 = [](size_t v) { return (v + 255) & ~(size_t)255; };
    char* p = (char*)d_ws;
    float* deg    = (float*)p; p += align256((size_t)N * 4);
    float* dinv   = (float*)p; p += align256((size_t)N * 4);
    int*   cnt    = (int*)p;   p += align256((size_t)N * 4);
    int*   rp     = (int*)p;   p += align256(((size_t)N + 1) * 4);
    int*   cursor = (int*)p;   p += align256((size_t)N * 4);
    int*   bsum   = (int*)p;   p += align256(SCAN_B * 4);
    int*   boff   = (int*)p;   p += align256(SCAN_B * 4);
    int*   col    = (int*)p;   p += align256((size_t)E * 4);
    float* val    = (float*)p; p += align256((size_t)E * 4);
    unsigned short* w1t_hi = (unsigned short*)p; p += align256((size_t)256 * 256 * 2);
    unsigned short* w1t_lo = (unsigned short*)p; p += align256((size_t)256 * 256 * 2);
    unsigned short* w2t_hi = (unsigned short*)p; p += align256((size_t)256 * 256 * 2);
    unsigned short* w2t_lo = (unsigned short*)p; p += align256((size_t)256 * 256 * 2);
    unsigned short* hbuf  = (unsigned short*)p; p += align256((size_t)N * 256 * 2);  // plain bf16 GEMM out
    unsigned short* a_hi  = (unsigned short*)p; p += align256((size_t)N * 256 * 2);
    unsigned short* a_lo  = (unsigned short*)p; p += align256((size_t)N * 256 * 2);
    (void)ws_size; (void)n_in; (void)out_size;

    const int nb_nodes = (N + 255) / 256;
    const int nb_edges = (E + 255) / 256;
    const int nb_scan  = (N + SCAN_B - 1) / SCAN_B;

    // graph normalization + CSR build
    init_kernel<<<nb_nodes, 256, 0, stream>>>(deg, cnt, N);
    deg_count_kernel<<<nb_edges, 256, 0, stream>>>(ei, w, deg, cnt, E);
    scan1_kernel<<<nb_scan, SCAN_B, 0, stream>>>(cnt, rp, bsum, deg, dinv, N);
    scan2_kernel<<<1, SCAN_B, 0, stream>>>(bsum, boff, nb_scan);
    scan3_kernel<<<nb_nodes, 256, 0, stream>>>(rp, cursor, boff, N, E);
    fill_kernel<<<nb_edges, 256, 0, stream>>>(ei, w, dinv, cursor, col, val, E);

    // weight prep (transpose + hi/lo split), both W in one launch
    prep_w_kernel<<<512, 256, 0, stream>>>(W1, W2, w1t_hi, w1t_lo, w2t_hi, w2t_lo);

    dim3 ggrid((N + 127) / 128, 2);
    const int nb_agg = (N + 3) / 4;

    // layer 1: GEMM (fp32 A, on-the-fly split) -> bf16 h -> agg (writes bf16 hi/lo)
    gemm_split_kernel<true><<<ggrid, 256, 0, stream>>>(x, nullptr, nullptr,
                                                       w1t_hi, w1t_lo, hbuf, N);
    agg_kernel<<<nb_agg, 256, 0, stream>>>(hbuf, rp, col, val, dinv, b1,
                                           a_hi, a_lo, nullptr, nullptr, nullptr, N);
    // layer 2: GEMM (pre-split bf16 A) -> bf16 h -> agg + fused head
    gemm_split_kernel<false><<<ggrid, 256, 0, stream>>>(nullptr, a_hi, a_lo,
                                                        w2t_hi, w2t_lo, hbuf, N);
    agg_kernel<<<nb_agg, 256, 0, stream>>>(hbuf, rp, col, val, dinv, b2,
                                           nullptr, nullptr, Wf, bf, out, N);
}

// Round 12
// 598.676 us; speedup vs baseline: 1.4122x; 1.2185x over previous
//
#include <hip/hip_runtime.h>
#include <hip/hip_bf16.h>
#include <cstdint>

#define IN_C 256

typedef __attribute__((ext_vector_type(8))) short bf16x8;
typedef __attribute__((ext_vector_type(8))) short s16x8;
typedef __attribute__((ext_vector_type(4))) short s16x4;
typedef __attribute__((ext_vector_type(8))) unsigned short u16x8;
typedef __attribute__((ext_vector_type(4))) float f32x4;

// ---- bf16 split helpers (RNE) ----
__device__ inline unsigned short f2bf(float f) {
    union { float f; unsigned int u; } v; v.f = f;
    unsigned int r = (v.u + 0x7fffu + ((v.u >> 16) & 1u)) >> 16;
    return (unsigned short)r;
}
__device__ inline float bf2f(unsigned short b) {
    union { unsigned int u; float f; } v; v.u = ((unsigned int)b) << 16;
    return v.f;
}
// returns .x = hi bf16 bits, .y = lo bf16 bits
__device__ inline short2 split1(float f) {
    unsigned short hb = f2bf(f);
    unsigned short lb = f2bf(f - bf2f(hb));
    return make_short2((short)hb, (short)lb);
}

// ---------------- per-edge: degree accumulate + dst histogram ----------------
// deg/cnt zeroed by hipMemsetAsync; self-loop's +1 folded into dinv (rsqrt(deg+1))
__global__ void deg_count_kernel(const int* __restrict__ ei, const float* __restrict__ w,
                                 float* __restrict__ deg, int* __restrict__ cnt, int E) {
    int e = blockIdx.x * blockDim.x + threadIdx.x;
    if (e >= E) return;
    int dst = ei[E + e];
    atomicAdd(&deg[dst], w[e]);
    atomicAdd(&cnt[dst], 1);
}

// ---------------- exclusive scan of cnt -> row_ptr (3-kernel); scan1 also dinv ----------------
#define SCAN_B 256
__global__ void scan1_kernel(const int* __restrict__ cnt, int* __restrict__ rp,
                             int* __restrict__ bsum,
                             const float* __restrict__ deg, float* __restrict__ dinv,
                             int N) {
    __shared__ int s[SCAN_B];
    int tid = threadIdx.x;
    int i = blockIdx.x * SCAN_B + tid;
    if (i < N) dinv[i] = rsqrtf(deg[i] + 1.0f);   // +1 = self loop weight
    int v = (i < N) ? cnt[i] : 0;
    s[tid] = v;
    __syncthreads();
    for (int off = 1; off < SCAN_B; off <<= 1) {
        int t = (tid >= off) ? s[tid - off] : 0;
        __syncthreads();
        s[tid] += t;
        __syncthreads();
    }
    if (i < N) rp[i] = s[tid] - v;            // exclusive within block
    if (tid == SCAN_B - 1) bsum[blockIdx.x] = s[tid];
}

__global__ void scan2_kernel(int* __restrict__ bsum, int* __restrict__ boff, int nb) {
    __shared__ int s[SCAN_B];
    int tid = threadIdx.x;
    int v = (tid < nb) ? bsum[tid] : 0;
    s[tid] = v;
    __syncthreads();
    for (int off = 1; off < SCAN_B; off <<= 1) {
        int t = (tid >= off) ? s[tid - off] : 0;
        __syncthreads();
        s[tid] += t;
        __syncthreads();
    }
    if (tid < nb) boff[tid] = s[tid] - v;     // exclusive across blocks
}

__global__ void scan3_kernel(int* __restrict__ rp, int* __restrict__ cursor,
                             const int* __restrict__ boff, int N, int E) {
    int i = blockIdx.x * blockDim.x + threadIdx.x;
    if (i < N) {
        int r = rp[i] + boff[i >> 8];
        rp[i] = r;
        cursor[i] = r;
    }
    if (i == 0) rp[N] = E;
}

// ---------------- CSR fill with per-edge norm; packed (col, val) int2 ----------------
__global__ void fill_kernel(const int* __restrict__ ei, const float* __restrict__ w,
                            const float* __restrict__ dinv, int* __restrict__ cursor,
                            int2* __restrict__ cv, int E) {
    int e = blockIdx.x * blockDim.x + threadIdx.x;
    if (e >= E) return;
    int src = ei[e];
    int dst = ei[E + e];
    int pos = atomicAdd(&cursor[dst], 1);
    // defensive clamp: never allow a wild store outside [0,E)
    if (pos >= 0 && pos < E) {
        float v = dinv[src] * w[e] * dinv[dst];
        cv[pos] = make_int2(src, __float_as_int(v));
    }
}

// ---------------- prep: W1/W2 transpose+split AND x split, one launch ----------------
// blocks [0,512): W prep (b<256 -> W1 col b; else W2 col b-256)
// blocks [512, 512+nx4/256): x split, one float4 per thread
__global__ void prep_kernel(const float* __restrict__ W1, const float* __restrict__ W2,
                            const float* __restrict__ x,
                            unsigned short* __restrict__ w1t_hi, unsigned short* __restrict__ w1t_lo,
                            unsigned short* __restrict__ w2t_hi, unsigned short* __restrict__ w2t_lo,
                            unsigned short* __restrict__ x_hi, unsigned short* __restrict__ x_lo,
                            int nx4) {
    int b = blockIdx.x;
    if (b < 512) {
        const float* W = (b < 256) ? W1 : W2;
        unsigned short* hi = (b < 256) ? w1t_hi : w2t_hi;
        unsigned short* lo = (b < 256) ? w1t_lo : w2t_lo;
        int n = b & 255;       // col of W
        int k = threadIdx.x;   // row of W
        float v = W[(size_t)k * 256 + n];
        short2 s = split1(v);
        hi[(size_t)n * 256 + k] = (unsigned short)s.x;
        lo[(size_t)n * 256 + k] = (unsigned short)s.y;
    } else {
        int i = (b - 512) * 256 + threadIdx.x;   // float4 index
        if (i < nx4) {
            float4 v = ((const float4*)x)[i];
            short2 sx = split1(v.x), sy = split1(v.y), sz = split1(v.z), sw = split1(v.w);
            s16x4 hv, lv;
            hv.x = sx.x; hv.y = sy.x; hv.z = sz.x; hv.w = sw.x;
            lv.x = sx.y; lv.y = sy.y; lv.z = sz.y; lv.w = sw.y;
            *(s16x4*)(x_hi + (size_t)i * 4) = hv;
            *(s16x4*)(x_lo + (size_t)i * 4) = lv;
        }
    }
}

// ---------------- split-bf16 MFMA GEMM ----------------
// C16[N][256] (plain bf16) = A[N][256] @ B[256][256] in ~fp32 precision via 3x bf16 MFMA.
// A pre-split hi/lo bf16 arrays. Block: 256 thr = 4 waves; tile 128 x 128; BK=64.
__global__ __launch_bounds__(256) void gemm_split_kernel(
    const unsigned short* __restrict__ Ahg,
    const unsigned short* __restrict__ Alg,
    const unsigned short* __restrict__ Bth,   // Wt_hi [n][k]
    const unsigned short* __restrict__ Btl,   // Wt_lo [n][k]
    unsigned short* __restrict__ C16, int Nrows)
{
    __shared__ __align__(16) short Ah[128 * 64];
    __shared__ __align__(16) short Al[128 * 64];
    __shared__ __align__(16) short Bh[128 * 64];
    __shared__ __align__(16) short Bl[128 * 64];

    const int t    = threadIdx.x;
    const int lane = t & 63;
    const int w    = t >> 6;
    const int r0   = blockIdx.x * 128;
    const int cb0  = blockIdx.y * 128;
    const int fr   = lane & 15;          // frag row (A: m-row / B: n-col)
    const int fk   = (lane >> 4) * 8;    // frag k offset
    const int wm   = w * 32;             // wave's m-band

    f32x4 acc[2][8] = {};

    for (int k0 = 0; k0 < 256; k0 += 64) {
        __syncthreads();
        // ---- stage B tile [128 n][64 k] (hi+lo) ----
#pragma unroll
        for (int c = 0; c < 4; ++c) {
            int i = c * 256 + t;
            int row = i >> 3, seg = i & 7;
            size_t g = (size_t)(cb0 + row) * 256 + k0 + seg * 8;
            *(s16x8*)&Bh[row * 64 + seg * 8] = *(const s16x8*)(Bth + g);
            *(s16x8*)&Bl[row * 64 + seg * 8] = *(const s16x8*)(Btl + g);
        }
        // ---- stage A tile [128 m][64 k] (hi+lo) ----
#pragma unroll
        for (int c = 0; c < 4; ++c) {
            int i = c * 256 + t;
            int row = i >> 3, seg = i & 7;
            int gr = r0 + row; if (gr > Nrows - 1) gr = Nrows - 1;
            size_t g = (size_t)gr * 256 + k0 + seg * 8;
            *(s16x8*)&Ah[row * 64 + seg * 8] = *(const s16x8*)(Ahg + g);
            *(s16x8*)&Al[row * 64 + seg * 8] = *(const s16x8*)(Alg + g);
        }
        __syncthreads();
        // ---- compute: 2 k-steps of 32, 2m x 8n frags, 3 MFMA each ----
#pragma unroll
        for (int ks = 0; ks < 2; ++ks) {
            int ko = ks * 32 + fk;
            bf16x8 ah[2], al[2];
#pragma unroll
            for (int mi = 0; mi < 2; ++mi) {
                ah[mi] = *(const bf16x8*)&Ah[(wm + mi * 16 + fr) * 64 + ko];
                al[mi] = *(const bf16x8*)&Al[(wm + mi * 16 + fr) * 64 + ko];
            }
#pragma unroll
            for (int n = 0; n < 8; ++n) {
                bf16x8 bh = *(const bf16x8*)&Bh[(n * 16 + fr) * 64 + ko];
                bf16x8 bl = *(const bf16x8*)&Bl[(n * 16 + fr) * 64 + ko];
#pragma unroll
                for (int mi = 0; mi < 2; ++mi) {
                    acc[mi][n] = __builtin_amdgcn_mfma_f32_16x16x32_bf16(ah[mi], bh, acc[mi][n], 0, 0, 0);
                    acc[mi][n] = __builtin_amdgcn_mfma_f32_16x16x32_bf16(ah[mi], bl, acc[mi][n], 0, 0, 0);
                    acc[mi][n] = __builtin_amdgcn_mfma_f32_16x16x32_bf16(al[mi], bh, acc[mi][n], 0, 0, 0);
                }
            }
        }
    }
    // ---- epilogue: C/D layout col=lane&15, row=(lane>>4)*4+reg; store plain bf16 ----
    const int rb = (lane >> 4) * 4;
#pragma unroll
    for (int mi = 0; mi < 2; ++mi) {
#pragma unroll
        for (int n = 0; n < 8; ++n) {
            int col = cb0 + n * 16 + fr;
#pragma unroll
            for (int r = 0; r < 4; ++r) {
                int row = r0 + wm + mi * 16 + rb + r;
                if (row < Nrows) C16[(size_t)row * 256 + col] = f2bf(acc[mi][n][r]);
            }
        }
    }
}

// ---- 8-channel bf16 FMA helper ----
__device__ inline void fma8(float* acc, u16x8 g, float v) {
#pragma unroll
    for (int c = 0; c < 8; ++c) acc[c] = fmaf(v, bf2f(g[c]), acc[c]);
}

// ---------------- CSR aggregation + self loop + bias + relu (+optional fused head) ----
// bf16-h gather, HALF-WAVE-per-edge structure: keeps the proven 16B/lane
// global_load_dwordx4 shape (8B ushort4 loads collapsed to ~2 in flight,
// 6.7x slower — R6/R7). One wave per dst node; lane l handles 8 channels
// [8*(l&31), +8) of edge j+2t+(l>>5); 16-edge main loop = 8 dwordx4 in
// flight, 8-edge mid tier = 4, then 2/1-edge tail. cv = packed (col, val);
// per-pair scalar loads + cndmask select per half.
// Epilogue: out_hi!=nullptr -> relu + bf16 hi/lo split; else fused head.
__global__ __launch_bounds__(256) void agg_kernel(const unsigned short* __restrict__ h16,
                                                  const int* __restrict__ rp,
                                                  const int2* __restrict__ cv,
                                                  const float* __restrict__ dinv,
                                                  const float* __restrict__ bias,
                                                  unsigned short* __restrict__ out_hi,
                                                  unsigned short* __restrict__ out_lo,
                                                  const float* __restrict__ Wf,
                                                  const float* __restrict__ bf,
                                                  float* __restrict__ out,
                                                  int N) {
    int d    = blockIdx.x * 4 + (threadIdx.x >> 6);
    int lane = threadIdx.x & 63;
    if (d >= N) return;
    int half = lane >> 5;
    int co   = (lane & 31) * 8;          // this lane's channel offset

    float di = dinv[d];
    float selfm = half ? 0.0f : di * di;           // count self loop once
    u16x8 sv = *(const u16x8*)(h16 + (size_t)d * 256 + co);
    float acc[8];
#pragma unroll
    for (int c = 0; c < 8; ++c) acc[c] = selfm * bf2f(sv[c]);

    int s = rp[d], e = rp[d + 1];
    int j = s;
    for (; j + 16 <= e; j += 16) {
        int   ec[8]; float ev[8];
#pragma unroll
        for (int t2 = 0; t2 < 8; ++t2) {
            int2 ca = cv[j + 2 * t2], cb = cv[j + 2 * t2 + 1];
            ec[t2] = half ? cb.x : ca.x;
            ev[t2] = __int_as_float(half ? cb.y : ca.y);
        }
        u16x8 g0 = *(const u16x8*)(h16 + (size_t)ec[0] * 256 + co);
        u16x8 g1 = *(const u16x8*)(h16 + (size_t)ec[1] * 256 + co);
        u16x8 g2 = *(const u16x8*)(h16 + (size_t)ec[2] * 256 + co);
        u16x8 g3 = *(const u16x8*)(h16 + (size_t)ec[3] * 256 + co);
        u16x8 g4 = *(const u16x8*)(h16 + (size_t)ec[4] * 256 + co);
        u16x8 g5 = *(const u16x8*)(h16 + (size_t)ec[5] * 256 + co);
        u16x8 g6 = *(const u16x8*)(h16 + (size_t)ec[6] * 256 + co);
        u16x8 g7 = *(const u16x8*)(h16 + (size_t)ec[7] * 256 + co);
        fma8(acc, g0, ev[0]);
        fma8(acc, g1, ev[1]);
        fma8(acc, g2, ev[2]);
        fma8(acc, g3, ev[3]);
        fma8(acc, g4, ev[4]);
        fma8(acc, g5, ev[5]);
        fma8(acc, g6, ev[6]);
        fma8(acc, g7, ev[7]);
    }
    for (; j + 8 <= e; j += 8) {
        int   ec[4]; float ev[4];
#pragma unroll
        for (int t2 = 0; t2 < 4; ++t2) {
            int2 ca = cv[j + 2 * t2], cb = cv[j + 2 * t2 + 1];
            ec[t2] = half ? cb.x : ca.x;
            ev[t2] = __int_as_float(half ? cb.y : ca.y);
        }
        u16x8 g0 = *(const u16x8*)(h16 + (size_t)ec[0] * 256 + co);
        u16x8 g1 = *(const u16x8*)(h16 + (size_t)ec[1] * 256 + co);
        u16x8 g2 = *(const u16x8*)(h16 + (size_t)ec[2] * 256 + co);
        u16x8 g3 = *(const u16x8*)(h16 + (size_t)ec[3] * 256 + co);
        fma8(acc, g0, ev[0]);
        fma8(acc, g1, ev[1]);
        fma8(acc, g2, ev[2]);
        fma8(acc, g3, ev[3]);
    }
    for (; j + 2 <= e; j += 2) {
        int2 ca = cv[j], cb = cv[j + 1];
        int   ee = half ? cb.x : ca.x;
        float vv = __int_as_float(half ? cb.y : ca.y);
        u16x8 g = *(const u16x8*)(h16 + (size_t)ee * 256 + co);
        fma8(acc, g, vv);
    }
    if (j < e) {                                    // single leftover edge
        int2 ca = cv[j];
        int   ee = ca.x;
        float vv = half ? 0.0f : __int_as_float(ca.y);
        u16x8 g = *(const u16x8*)(h16 + (size_t)ee * 256 + co);
        fma8(acc, g, vv);
    }

    // combine halves: both halves end with the full per-channel sums
#pragma unroll
    for (int c = 0; c < 8; ++c) acc[c] += __shfl_xor(acc[c], 32);

    float4 b0 = *(const float4*)(bias + co);
    float4 b1 = *(const float4*)(bias + co + 4);
    acc[0] = fmaxf(acc[0] + b0.x, 0.0f);
    acc[1] = fmaxf(acc[1] + b0.y, 0.0f);
    acc[2] = fmaxf(acc[2] + b0.z, 0.0f);
    acc[3] = fmaxf(acc[3] + b0.w, 0.0f);
    acc[4] = fmaxf(acc[4] + b1.x, 0.0f);
    acc[5] = fmaxf(acc[5] + b1.y, 0.0f);
    acc[6] = fmaxf(acc[6] + b1.z, 0.0f);
    acc[7] = fmaxf(acc[7] + b1.w, 0.0f);

    if (out_hi != nullptr) {
        u16x8 hi;
#pragma unroll
        for (int c = 0; c < 8; ++c) hi[c] = f2bf(acc[c]);
        if (half == 0) {
            *(u16x8*)(out_hi + (size_t)d * 256 + co) = hi;
        } else {
            u16x8 lo;
#pragma unroll
            for (int c = 0; c < 8; ++c) lo[c] = f2bf(acc[c] - bf2f(hi[c]));
            *(u16x8*)(out_lo + (size_t)d * 256 + co) = lo;
        }
    } else {
        float4 wf0 = *(const float4*)(Wf + co);
        float4 wf1 = *(const float4*)(Wf + co + 4);
        float sdot = acc[0] * wf0.x + acc[1] * wf0.y + acc[2] * wf0.z + acc[3] * wf0.w
                   + acc[4] * wf1.x + acc[5] * wf1.y + acc[6] * wf1.z + acc[7] * wf1.w;
        for (int o = 16; o; o >>= 1) sdot += __shfl_down(sdot, o);   // per-half reduce
        if (lane == 0) out[d] = sdot + bf[0];
    }
}

// ---------------- host launch ----------------
extern "C" void kernel_launch(void* const* d_in, const int* in_sizes, int n_in,
                              void* d_out, int out_size, void* d_ws, size_t ws_size,
                              hipStream_t stream) {
    const float* x  = (const float*)d_in[0];
    const int*   ei = (const int*)d_in[1];
    const float* w  = (const float*)d_in[2];
    const float* W1 = (const float*)d_in[3];
    const float* b1 = (const float*)d_in[4];
    const float* W2 = (const float*)d_in[5];
    const float* b2 = (const float*)d_in[6];
    const float* Wf = (const float*)d_in[7];
    const float* bf = (const float*)d_in[8];
    float* out = (float*)d_out;

    const int N = in_sizes[0] / IN_C;
    const int E = in_sizes[2];

    // workspace layout (256B aligned)
    auto align256 = [](size_t v) { return (v + 255) & ~(size_t)255; };
    char* p = (char*)d_ws;
    float* deg    = (float*)p; p += align256((size_t)N * 4);
    int*   cnt    = (int*)p;   p += align256((size_t)N * 4);   // adjacent to deg: one memset
    float* dinv   = (float*)p; p += align256((size_t)N * 4);
    int*   rp     = (int*)p;   p += align256(((size_t)N + 1) * 4);
    int*   cursor = (int*)p;   p += align256((size_t)N * 4);
    int*   bsum   = (int*)p;   p += align256(SCAN_B * 4);
    int*   boff   = (int*)p;   p += align256(SCAN_B * 4);
    int2*  cv     = (int2*)p;  p += align256((size_t)E * 8);
    unsigned short* w1t_hi = (unsigned short*)p; p += align256((size_t)256 * 256 * 2);
    unsigned short* w1t_lo = (unsigned short*)p; p += align256((size_t)256 * 256 * 2);
    unsigned short* w2t_hi = (unsigned short*)p; p += align256((size_t)256 * 256 * 2);
    unsigned short* w2t_lo = (unsigned short*)p; p += align256((size_t)256 * 256 * 2);
    unsigned short* hbuf  = (unsigned short*)p; p += align256((size_t)N * 256 * 2);  // plain bf16 GEMM out
    // xa_hi/xa_lo: x pre-split (read by GEMM1), then REUSED by agg1 as a_hi/a_lo
    // (x_hi/x_lo dead after GEMM1; same stream serializes; prep rewrites each call)
    unsigned short* xa_hi = (unsigned short*)p; p += align256((size_t)N * 256 * 2);
    unsigned short* xa_lo = (unsigned short*)p; p += align256((size_t)N * 256 * 2);
    (void)ws_size; (void)n_in; (void)out_size;

    const int nb_edges = (E + 255) / 256;
    const int nb_nodes = (N + 255) / 256;
    const int nb_scan  = (N + SCAN_B - 1) / SCAN_B;
    const int nx4      = N * 256 / 4;

    // zero deg+cnt (adjacent, includes alignment pad)
    hipMemsetAsync(deg, 0, 2 * align256((size_t)N * 4), stream);

    // graph normalization + CSR build
    deg_count_kernel<<<nb_edges, 256, 0, stream>>>(ei, w, deg, cnt, E);
    scan1_kernel<<<nb_scan, SCAN_B, 0, stream>>>(cnt, rp, bsum, deg, dinv, N);
    scan2_kernel<<<1, SCAN_B, 0, stream>>>(bsum, boff, nb_scan);
    scan3_kernel<<<nb_nodes, 256, 0, stream>>>(rp, cursor, boff, N, E);
    fill_kernel<<<nb_edges, 256, 0, stream>>>(ei, w, dinv, cursor, cv, E);

    // prep: W1/W2 transpose+split and x split, one launch
    prep_kernel<<<512 + (nx4 + 255) / 256, 256, 0, stream>>>(
        W1, W2, x, w1t_hi, w1t_lo, w2t_hi, w2t_lo, xa_hi, xa_lo, nx4);

    dim3 ggrid((N + 127) / 128, 2);
    const int nb_agg = (N + 3) / 4;

    // layer 1: GEMM (pre-split x) -> bf16 h -> agg (writes bf16 hi/lo into xa_*)
    gemm_split_kernel<<<ggrid, 256, 0, stream>>>(xa_hi, xa_lo, w1t_hi, w1t_lo, hbuf, N);
    agg_kernel<<<nb_agg, 256, 0, stream>>>(hbuf, rp, cv, dinv, b1,
                                           xa_hi, xa_lo, nullptr, nullptr, nullptr, N);
    // layer 2: GEMM (pre-split a) -> bf16 h -> agg + fused head
    gemm_split_kernel<<<ggrid, 256, 0, stream>>>(xa_hi, xa_lo, w2t_hi, w2t_lo, hbuf, N);
    agg_kernel<<<nb_agg, 256, 0, stream>>>(hbuf, rp, cv, dinv, b2,
                                           nullptr, nullptr, Wf, bf, out, N);
}

// Round 13
// 473.437 us; speedup vs baseline: 1.7858x; 1.2645x over previous
//
#include <hip/hip_runtime.h>
#include <hip/hip_bf16.h>
#include <cstdint>

#define IN_C 256

typedef __attribute__((ext_vector_type(8))) short bf16x8;
typedef __attribute__((ext_vector_type(8))) short s16x8;
typedef __attribute__((ext_vector_type(4))) short s16x4;
typedef __attribute__((ext_vector_type(8))) unsigned short u16x8;
typedef __attribute__((ext_vector_type(4))) float f32x4;

#define FIXED_SCALE 33554432.0f          // 2^25
#define FIXED_INV   (1.0f / 33554432.0f)
#define DEG_MASK    ((1ULL << 40) - 1)

// ---- bf16 split helpers (RNE) ----
__device__ inline unsigned short f2bf(float f) {
    union { float f; unsigned int u; } v; v.f = f;
    unsigned int r = (v.u + 0x7fffu + ((v.u >> 16) & 1u)) >> 16;
    return (unsigned short)r;
}
__device__ inline float bf2f(unsigned short b) {
    union { unsigned int u; float f; } v; v.u = ((unsigned int)b) << 16;
    return v.f;
}
// returns .x = hi bf16 bits, .y = lo bf16 bits
__device__ inline short2 split1(float f) {
    unsigned short hb = f2bf(f);
    unsigned short lb = f2bf(f - bf2f(hb));
    return make_short2((short)hb, (short)lb);
}

// ---------------- per-edge: ONE packed u64 atomic = deg (fixed-point) + cnt + rank ----
// packed[d]: low 40 bits = sum of round(w*2^25), high bits = edge count.
// atomicAdd return's high field = this edge's rank among its dst's edges.
__global__ void deg_count_kernel(const int* __restrict__ ei, const float* __restrict__ w,
                                 unsigned long long* __restrict__ packed,
                                 unsigned short* __restrict__ rank, int E) {
    int e = blockIdx.x * blockDim.x + threadIdx.x;
    if (e >= E) return;
    int dst = ei[E + e];
    unsigned int fx = __float2uint_rn(w[e] * FIXED_SCALE);
    unsigned long long inc = (1ULL << 40) | (unsigned long long)fx;
    unsigned long long old = atomicAdd(&packed[dst], inc);
    rank[e] = (unsigned short)(old >> 40);
}

// ---------------- exclusive scan of cnt -> row_ptr (3-kernel); scan1 also dinv ----------------
#define SCAN_B 256
__global__ void scan1_kernel(const unsigned long long* __restrict__ packed,
                             int* __restrict__ rp, int* __restrict__ bsum,
                             float* __restrict__ dinv, int N) {
    __shared__ int s[SCAN_B];
    int tid = threadIdx.x;
    int i = blockIdx.x * SCAN_B + tid;
    int v = 0;
    if (i < N) {
        unsigned long long pk = packed[i];
        v = (int)(pk >> 40);
        float deg = (float)(pk & DEG_MASK) * FIXED_INV;
        dinv[i] = rsqrtf(deg + 1.0f);         // +1 = self loop weight
    }
    s[tid] = v;
    __syncthreads();
    for (int off = 1; off < SCAN_B; off <<= 1) {
        int t = (tid >= off) ? s[tid - off] : 0;
        __syncthreads();
        s[tid] += t;
        __syncthreads();
    }
    if (i < N) rp[i] = s[tid] - v;            // exclusive within block
    if (tid == SCAN_B - 1) bsum[blockIdx.x] = s[tid];
}

__global__ void scan2_kernel(int* __restrict__ bsum, int* __restrict__ boff, int nb) {
    __shared__ int s[SCAN_B];
    int tid = threadIdx.x;
    int v = (tid < nb) ? bsum[tid] : 0;
    s[tid] = v;
    __syncthreads();
    for (int off = 1; off < SCAN_B; off <<= 1) {
        int t = (tid >= off) ? s[tid - off] : 0;
        __syncthreads();
        s[tid] += t;
        __syncthreads();
    }
    if (tid < nb) boff[tid] = s[tid] - v;     // exclusive across blocks
}

__global__ void scan3_kernel(int* __restrict__ rp, const int* __restrict__ boff,
                             int N, int E) {
    int i = blockIdx.x * blockDim.x + threadIdx.x;
    if (i < N) rp[i] = rp[i] + boff[i >> 8];
    if (i == 0) rp[N] = E;
}

// ---------------- CSR fill, ATOMIC-FREE: pos = rp[dst] + rank[e] ----------------
__global__ void fill_kernel(const int* __restrict__ ei, const float* __restrict__ w,
                            const float* __restrict__ dinv,
                            const int* __restrict__ rp,
                            const unsigned short* __restrict__ rank,
                            int2* __restrict__ cv, int E) {
    int e = blockIdx.x * blockDim.x + threadIdx.x;
    if (e >= E) return;
    int src = ei[e];
    int dst = ei[E + e];
    int pos = rp[dst] + (int)rank[e];
    // defensive clamp: never allow a wild store outside [0,E)
    if ((unsigned)pos < (unsigned)E) {
        float v = dinv[src] * w[e] * dinv[dst];
        cv[pos] = make_int2(src, __float_as_int(v));
    }
}

// ---------------- prep: W1/W2 transpose+split AND x split, one launch ----------------
// blocks [0,512): W prep (b<256 -> W1 col b; else W2 col b-256)
// blocks [512, 512+nx4/256): x split, one float4 per thread
__global__ void prep_kernel(const float* __restrict__ W1, const float* __restrict__ W2,
                            const float* __restrict__ x,
                            unsigned short* __restrict__ w1t_hi, unsigned short* __restrict__ w1t_lo,
                            unsigned short* __restrict__ w2t_hi, unsigned short* __restrict__ w2t_lo,
                            unsigned short* __restrict__ x_hi, unsigned short* __restrict__ x_lo,
                            int nx4) {
    int b = blockIdx.x;
    if (b < 512) {
        const float* W = (b < 256) ? W1 : W2;
        unsigned short* hi = (b < 256) ? w1t_hi : w2t_hi;
        unsigned short* lo = (b < 256) ? w1t_lo : w2t_lo;
        int n = b & 255;       // col of W
        int k = threadIdx.x;   // row of W
        float v = W[(size_t)k * 256 + n];
        short2 s = split1(v);
        hi[(size_t)n * 256 + k] = (unsigned short)s.x;
        lo[(size_t)n * 256 + k] = (unsigned short)s.y;
    } else {
        int i = (b - 512) * 256 + threadIdx.x;   // float4 index
        if (i < nx4) {
            float4 v = ((const float4*)x)[i];
            short2 sx = split1(v.x), sy = split1(v.y), sz = split1(v.z), sw = split1(v.w);
            s16x4 hv, lv;
            hv.x = sx.x; hv.y = sy.x; hv.z = sz.x; hv.w = sw.x;
            lv.x = sx.y; lv.y = sy.y; lv.z = sz.y; lv.w = sw.y;
            *(s16x4*)(x_hi + (size_t)i * 4) = hv;
            *(s16x4*)(x_lo + (size_t)i * 4) = lv;
        }
    }
}

// ---------------- split-bf16 MFMA GEMM ----------------
// C16[N][256] (plain bf16) = A[N][256] @ B[256][256] in ~fp32 precision via 3x bf16 MFMA.
// A pre-split hi/lo bf16 arrays. Block: 256 thr = 4 waves; tile 128 x 128; BK=64.
__global__ __launch_bounds__(256) void gemm_split_kernel(
    const unsigned short* __restrict__ Ahg,
    const unsigned short* __restrict__ Alg,
    const unsigned short* __restrict__ Bth,   // Wt_hi [n][k]
    const unsigned short* __restrict__ Btl,   // Wt_lo [n][k]
    unsigned short* __restrict__ C16, int Nrows)
{
    __shared__ __align__(16) short Ah[128 * 64];
    __shared__ __align__(16) short Al[128 * 64];
    __shared__ __align__(16) short Bh[128 * 64];
    __shared__ __align__(16) short Bl[128 * 64];

    const int t    = threadIdx.x;
    const int lane = t & 63;
    const int w    = t >> 6;
    const int r0   = blockIdx.x * 128;
    const int cb0  = blockIdx.y * 128;
    const int fr   = lane & 15;          // frag row (A: m-row / B: n-col)
    const int fk   = (lane >> 4) * 8;    // frag k offset
    const int wm   = w * 32;             // wave's m-band

    f32x4 acc[2][8] = {};

    for (int k0 = 0; k0 < 256; k0 += 64) {
        __syncthreads();
        // ---- stage B tile [128 n][64 k] (hi+lo) ----
#pragma unroll
        for (int c = 0; c < 4; ++c) {
            int i = c * 256 + t;
            int row = i >> 3, seg = i & 7;
            size_t g = (size_t)(cb0 + row) * 256 + k0 + seg * 8;
            *(s16x8*)&Bh[row * 64 + seg * 8] = *(const s16x8*)(Bth + g);
            *(s16x8*)&Bl[row * 64 + seg * 8] = *(const s16x8*)(Btl + g);
        }
        // ---- stage A tile [128 m][64 k] (hi+lo) ----
#pragma unroll
        for (int c = 0; c < 4; ++c) {
            int i = c * 256 + t;
            int row = i >> 3, seg = i & 7;
            int gr = r0 + row; if (gr > Nrows - 1) gr = Nrows - 1;
            size_t g = (size_t)gr * 256 + k0 + seg * 8;
            *(s16x8*)&Ah[row * 64 + seg * 8] = *(const s16x8*)(Ahg + g);
            *(s16x8*)&Al[row * 64 + seg * 8] = *(const s16x8*)(Alg + g);
        }
        __syncthreads();
        // ---- compute: 2 k-steps of 32, 2m x 8n frags, 3 MFMA each ----
#pragma unroll
        for (int ks = 0; ks < 2; ++ks) {
            int ko = ks * 32 + fk;
            bf16x8 ah[2], al[2];
#pragma unroll
            for (int mi = 0; mi < 2; ++mi) {
                ah[mi] = *(const bf16x8*)&Ah[(wm + mi * 16 + fr) * 64 + ko];
                al[mi] = *(const bf16x8*)&Al[(wm + mi * 16 + fr) * 64 + ko];
            }
#pragma unroll
            for (int n = 0; n < 8; ++n) {
                bf16x8 bh = *(const bf16x8*)&Bh[(n * 16 + fr) * 64 + ko];
                bf16x8 bl = *(const bf16x8*)&Bl[(n * 16 + fr) * 64 + ko];
#pragma unroll
                for (int mi = 0; mi < 2; ++mi) {
                    acc[mi][n] = __builtin_amdgcn_mfma_f32_16x16x32_bf16(ah[mi], bh, acc[mi][n], 0, 0, 0);
                    acc[mi][n] = __builtin_amdgcn_mfma_f32_16x16x32_bf16(ah[mi], bl, acc[mi][n], 0, 0, 0);
                    acc[mi][n] = __builtin_amdgcn_mfma_f32_16x16x32_bf16(al[mi], bh, acc[mi][n], 0, 0, 0);
                }
            }
        }
    }
    // ---- epilogue: C/D layout col=lane&15, row=(lane>>4)*4+reg; store plain bf16 ----
    const int rb = (lane >> 4) * 4;
#pragma unroll
    for (int mi = 0; mi < 2; ++mi) {
#pragma unroll
        for (int n = 0; n < 8; ++n) {
            int col = cb0 + n * 16 + fr;
#pragma unroll
            for (int r = 0; r < 4; ++r) {
                int row = r0 + wm + mi * 16 + rb + r;
                if (row < Nrows) C16[(size_t)row * 256 + col] = f2bf(acc[mi][n][r]);
            }
        }
    }
}

// ---- 8-channel bf16 FMA helper ----
__device__ inline void fma8(float* acc, u16x8 g, float v) {
#pragma unroll
    for (int c = 0; c < 8; ++c) acc[c] = fmaf(v, bf2f(g[c]), acc[c]);
}

// ---------------- CSR aggregation + self loop + bias + relu (+optional fused head) ----
// bf16-h gather, HALF-WAVE-per-edge structure: keeps the proven 16B/lane
// global_load_dwordx4 shape (8B ushort4 loads collapsed to ~2 in flight,
// 6.7x slower — R6/R7). One wave per dst node; lane l handles 8 channels
// [8*(l&31), +8) of edge j+2t+(l>>5); 16-edge main loop = 8 dwordx4 in
// flight, 8-edge mid tier = 4, then 2/1-edge tail. cv = packed (col, val).
// Epilogue: out_hi!=nullptr -> relu + bf16 hi/lo split; else fused head.
__global__ __launch_bounds__(256) void agg_kernel(const unsigned short* __restrict__ h16,
                                                  const int* __restrict__ rp,
                                                  const int2* __restrict__ cv,
                                                  const float* __restrict__ dinv,
                                                  const float* __restrict__ bias,
                                                  unsigned short* __restrict__ out_hi,
                                                  unsigned short* __restrict__ out_lo,
                                                  const float* __restrict__ Wf,
                                                  const float* __restrict__ bf,
                                                  float* __restrict__ out,
                                                  int N) {
    int d    = blockIdx.x * 4 + (threadIdx.x >> 6);
    int lane = threadIdx.x & 63;
    if (d >= N) return;
    int half = lane >> 5;
    int co   = (lane & 31) * 8;          // this lane's channel offset

    float di = dinv[d];
    float selfm = half ? 0.0f : di * di;           // count self loop once
    u16x8 sv = *(const u16x8*)(h16 + (size_t)d * 256 + co);
    float acc[8];
#pragma unroll
    for (int c = 0; c < 8; ++c) acc[c] = selfm * bf2f(sv[c]);

    int s = rp[d], e = rp[d + 1];
    int j = s;
    for (; j + 16 <= e; j += 16) {
        int   ec[8]; float ev[8];
#pragma unroll
        for (int t2 = 0; t2 < 8; ++t2) {
            int2 ca = cv[j + 2 * t2], cb = cv[j + 2 * t2 + 1];
            ec[t2] = half ? cb.x : ca.x;
            ev[t2] = __int_as_float(half ? cb.y : ca.y);
        }
        u16x8 g0 = *(const u16x8*)(h16 + (size_t)ec[0] * 256 + co);
        u16x8 g1 = *(const u16x8*)(h16 + (size_t)ec[1] * 256 + co);
        u16x8 g2 = *(const u16x8*)(h16 + (size_t)ec[2] * 256 + co);
        u16x8 g3 = *(const u16x8*)(h16 + (size_t)ec[3] * 256 + co);
        u16x8 g4 = *(const u16x8*)(h16 + (size_t)ec[4] * 256 + co);
        u16x8 g5 = *(const u16x8*)(h16 + (size_t)ec[5] * 256 + co);
        u16x8 g6 = *(const u16x8*)(h16 + (size_t)ec[6] * 256 + co);
        u16x8 g7 = *(const u16x8*)(h16 + (size_t)ec[7] * 256 + co);
        fma8(acc, g0, ev[0]);
        fma8(acc, g1, ev[1]);
        fma8(acc, g2, ev[2]);
        fma8(acc, g3, ev[3]);
        fma8(acc, g4, ev[4]);
        fma8(acc, g5, ev[5]);
        fma8(acc, g6, ev[6]);
        fma8(acc, g7, ev[7]);
    }
    for (; j + 8 <= e; j += 8) {
        int   ec[4]; float ev[4];
#pragma unroll
        for (int t2 = 0; t2 < 4; ++t2) {
            int2 ca = cv[j + 2 * t2], cb = cv[j + 2 * t2 + 1];
            ec[t2] = half ? cb.x : ca.x;
            ev[t2] = __int_as_float(half ? cb.y : ca.y);
        }
        u16x8 g0 = *(const u16x8*)(h16 + (size_t)ec[0] * 256 + co);
        u16x8 g1 = *(const u16x8*)(h16 + (size_t)ec[1] * 256 + co);
        u16x8 g2 = *(const u16x8*)(h16 + (size_t)ec[2] * 256 + co);
        u16x8 g3 = *(const u16x8*)(h16 + (size_t)ec[3] * 256 + co);
        fma8(acc, g0, ev[0]);
        fma8(acc, g1, ev[1]);
        fma8(acc, g2, ev[2]);
        fma8(acc, g3, ev[3]);
    }
    for (; j + 2 <= e; j += 2) {
        int2 ca = cv[j], cb = cv[j + 1];
        int   ee = half ? cb.x : ca.x;
        float vv = __int_as_float(half ? cb.y : ca.y);
        u16x8 g = *(const u16x8*)(h16 + (size_t)ee * 256 + co);
        fma8(acc, g, vv);
    }
    if (j < e) {                                    // single leftover edge
        int2 ca = cv[j];
        int   ee = ca.x;
        float vv = half ? 0.0f : __int_as_float(ca.y);
        u16x8 g = *(const u16x8*)(h16 + (size_t)ee * 256 + co);
        fma8(acc, g, vv);
    }

    // combine halves: both halves end with the full per-channel sums
#pragma unroll
    for (int c = 0; c < 8; ++c) acc[c] += __shfl_xor(acc[c], 32);

    float4 b0 = *(const float4*)(bias + co);
    float4 b1 = *(const float4*)(bias + co + 4);
    acc[0] = fmaxf(acc[0] + b0.x, 0.0f);
    acc[1] = fmaxf(acc[1] + b0.y, 0.0f);
    acc[2] = fmaxf(acc[2] + b0.z, 0.0f);
    acc[3] = fmaxf(acc[3] + b0.w, 0.0f);
    acc[4] = fmaxf(acc[4] + b1.x, 0.0f);
    acc[5] = fmaxf(acc[5] + b1.y, 0.0f);
    acc[6] = fmaxf(acc[6] + b1.z, 0.0f);
    acc[7] = fmaxf(acc[7] + b1.w, 0.0f);

    if (out_hi != nullptr) {
        u16x8 hi;
#pragma unroll
        for (int c = 0; c < 8; ++c) hi[c] = f2bf(acc[c]);
        if (half == 0) {
            *(u16x8*)(out_hi + (size_t)d * 256 + co) = hi;
        } else {
            u16x8 lo;
#pragma unroll
            for (int c = 0; c < 8; ++c) lo[c] = f2bf(acc[c] - bf2f(hi[c]));
            *(u16x8*)(out_lo + (size_t)d * 256 + co) = lo;
        }
    } else {
        float4 wf0 = *(const float4*)(Wf + co);
        float4 wf1 = *(const float4*)(Wf + co + 4);
        float sdot = acc[0] * wf0.x + acc[1] * wf0.y + acc[2] * wf0.z + acc[3] * wf0.w
                   + acc[4] * wf1.x + acc[5] * wf1.y + acc[6] * wf1.z + acc[7] * wf1.w;
        for (int o = 16; o; o >>= 1) sdot += __shfl_down(sdot, o);   // per-half reduce
        if (lane == 0) out[d] = sdot + bf[0];
    }
}

// ---------------- host launch ----------------
extern "C" void kernel_launch(void* const* d_in, const int* in_sizes, int n_in,
                              void* d_out, int out_size, void* d_ws, size_t ws_size,
                              hipStream_t stream) {
    const float* x  = (const float*)d_in[0];
    const int*   ei = (const int*)d_in[1];
    const float* w  = (const float*)d_in[2];
    const float* W1 = (const float*)d_in[3];
    const float* b1 = (const float*)d_in[4];
    const float* W2 = (const float*)d_in[5];
    const float* b2 = (const float*)d_in[6];
    const float* Wf = (const float*)d_in[7];
    const float* bf = (const float*)d_in[8];
    float* out = (float*)d_out;

    const int N = in_sizes[0] / IN_C;
    const int E = in_sizes[2];

    // workspace layout (256B aligned)
    auto align256 = [](size_t v) { return (v + 255) & ~(size_t)255; };
    char* p = (char*)d_ws;
    unsigned long long* packed = (unsigned long long*)p; p += align256((size_t)N * 8);
    float* dinv   = (float*)p; p += align256((size_t)N * 4);
    int*   rp     = (int*)p;   p += align256(((size_t)N + 1) * 4);
    int*   bsum   = (int*)p;   p += align256(SCAN_B * 4);
    int*   boff   = (int*)p;   p += align256(SCAN_B * 4);
    unsigned short* rank = (unsigned short*)p; p += align256((size_t)E * 2);
    int2*  cv     = (int2*)p;  p += align256((size_t)E * 8);
    unsigned short* w1t_hi = (unsigned short*)p; p += align256((size_t)256 * 256 * 2);
    unsigned short* w1t_lo = (unsigned short*)p; p += align256((size_t)256 * 256 * 2);
    unsigned short* w2t_hi = (unsigned short*)p; p += align256((size_t)256 * 256 * 2);
    unsigned short* w2t_lo = (unsigned short*)p; p += align256((size_t)256 * 256 * 2);
    unsigned short* hbuf  = (unsigned short*)p; p += align256((size_t)N * 256 * 2);  // plain bf16 GEMM out
    // xa_hi/xa_lo: x pre-split (read by GEMM1), then REUSED by agg1 as a_hi/a_lo
    unsigned short* xa_hi = (unsigned short*)p; p += align256((size_t)N * 256 * 2);
    unsigned short* xa_lo = (unsigned short*)p; p += align256((size_t)N * 256 * 2);
    (void)ws_size; (void)n_in; (void)out_size;

    const int nb_edges = (E + 255) / 256;
    const int nb_nodes = (N + 255) / 256;
    const int nb_scan  = (N + SCAN_B - 1) / SCAN_B;
    const int nx4      = N * 256 / 4;

    // zero packed deg/cnt accumulators
    hipMemsetAsync(packed, 0, (size_t)N * 8, stream);

    // graph normalization + CSR build (single atomic pass; fill is atomic-free)
    deg_count_kernel<<<nb_edges, 256, 0, stream>>>(ei, w, packed, rank, E);
    scan1_kernel<<<nb_scan, SCAN_B, 0, stream>>>(packed, rp, bsum, dinv, N);
    scan2_kernel<<<1, SCAN_B, 0, stream>>>(bsum, boff, nb_scan);
    scan3_kernel<<<nb_nodes, 256, 0, stream>>>(rp, boff, N, E);
    fill_kernel<<<nb_edges, 256, 0, stream>>>(ei, w, dinv, rp, rank, cv, E);

    // prep: W1/W2 transpose+split and x split, one launch
    prep_kernel<<<512 + (nx4 + 255) / 256, 256, 0, stream>>>(
        W1, W2, x, w1t_hi, w1t_lo, w2t_hi, w2t_lo, xa_hi, xa_lo, nx4);

    dim3 ggrid((N + 127) / 128, 2);
    const int nb_agg = (N + 3) / 4;

    // layer 1: GEMM (pre-split x) -> bf16 h -> agg (writes bf16 hi/lo into xa_*)
    gemm_split_kernel<<<ggrid, 256, 0, stream>>>(xa_hi, xa_lo, w1t_hi, w1t_lo, hbuf, N);
    agg_kernel<<<nb_agg, 256, 0, stream>>>(hbuf, rp, cv, dinv, b1,
                                           xa_hi, xa_lo, nullptr, nullptr, nullptr, N);
    // layer 2: GEMM (pre-split a) -> bf16 h -> agg + fused head
    gemm_split_kernel<<<ggrid, 256, 0, stream>>>(xa_hi, xa_lo, w2t_hi, w2t_lo, hbuf, N);
    agg_kernel<<<nb_agg, 256, 0, stream>>>(hbuf, rp, cv, dinv, b2,
                                           nullptr, nullptr, Wf, bf, out, N);
}